// Round 13
// baseline (415.695 us; speedup 1.0000x reference)
//
#include <hip/hip_runtime.h>

#define NNODES 50000
#define NEDGES 800000
#define HD 128
#define NG 512
#define BN_EPS 1e-5f
#define NTILE 3125           // 16-row tiles: 50000 = 3125 * 16 exactly
#define NSPLIT 8             // stats atomic split
#define NSB 49               // scan blocks
#define AROW 136             // padded LDS tile row in ushorts (272 B)

typedef short bf16x8 __attribute__((ext_vector_type(8)));
typedef float floatx4 __attribute__((ext_vector_type(4)));

union U16 { uint4 u; bf16x8 h; };

__device__ __forceinline__ ushort f2bf(float f) {
    unsigned u = __float_as_uint(f);
    return (ushort)((u + 0x7fffu + ((u >> 16) & 1u)) >> 16);
}
__device__ __forceinline__ void unpack8(const uint4& u, float* f) {
    const unsigned* w = (const unsigned*)&u;
#pragma unroll
    for (int i = 0; i < 4; ++i) {
        f[2 * i]     = __uint_as_float(w[i] << 16);
        f[2 * i + 1] = __uint_as_float(w[i] & 0xffff0000u);
    }
}
__device__ __forceinline__ uint4 pack8(const float* f) {
    uint4 o;
    unsigned* w = (unsigned*)&o;
#pragma unroll
    for (int i = 0; i < 4; ++i)
        w[i] = (unsigned)f2bf(f[2 * i]) | ((unsigned)f2bf(f[2 * i + 1]) << 16);
    return o;
}

// ---------------- prep: hist(+rank) + wfrag(5) + gemm0A, one dispatch -----------
// blocks [0,3125): histogram of edge dst, record per-edge rank
// blocks [3125,3130): pack W[1..5] into MFMA B-frag order
// blocks [3130,6255): gemm0A — y0 = x @ Wa0, Wa0 self-staged fp32->bf16 in LDS

struct WP6 { const float* w[6]; };

__global__ __launch_bounds__(256, 3) void prep_kernel(
    const int* __restrict__ edst, int* __restrict__ cnt, int* __restrict__ rank,
    WP6 p, ushort* __restrict__ wf,
    const float* __restrict__ x, ushort* __restrict__ y) {
    __shared__ ushort wls[16384];     // 32 KB Wa0 frags
    __shared__ ushort abuf[16 * AROW];
    __shared__ ushort cbuf[16 * HD];
    const int b = blockIdx.x, t = threadIdx.x;

    if (b < 3125) {
        int i = b * 256 + t;
        rank[i] = atomicAdd(&cnt[edst[i]], 1);
        return;
    }
    if (b < 3130) {
        int m = b - 3125 + 1;          // matrices 1..5
        const float* W = p.w[m];
        ushort* o = wf + (size_t)m * 16384;
        for (int i = t; i < 16384; i += 256) {
            int j = i & 7, lane = (i >> 3) & 63, kc = (i >> 9) & 3, ct = i >> 11;
            int k = kc * 32 + (lane >> 4) * 8 + j;
            int n = ct * 16 + (lane & 15);
            o[i] = f2bf(W[k * HD + n]);
        }
        return;
    }

    // ---- gemm0A ----
    const int row0 = (b - 3130) * 16;
    const int wave = t >> 6, lane = t & 63;
    const int quad = lane >> 4, l16 = lane & 15;

    // stage Wa0 into LDS in frag order: thread t covers floats [t*64, t*64+64)
    {
        const float* W = p.w[0];
        int k = t >> 1;                     // fixed row per thread
        int n0 = (t & 1) * 64;
        int kc = k >> 5, quad_w = (k >> 3) & 3, j = k & 7;
        int base = quad_w * 16 * 8 + j;     // (quad*16+l16)*8+j with l16 folded below
#pragma unroll
        for (int e = 0; e < 64; e += 4) {
            float4 v = *(const float4*)(W + (size_t)k * HD + n0 + e);
            float f[4] = {v.x, v.y, v.z, v.w};
#pragma unroll
            for (int q = 0; q < 4; ++q) {
                int n = n0 + e + q;
                int ct = n >> 4, lw = n & 15;
                wls[((ct * 4 + kc) * 64) * 8 + base + lw * 8] = f2bf(f[q]);
            }
        }
    }

    // x tile: thread t -> row t>>4, floats (t&15)*8 .. +8
    {
        int r = t >> 4, l = t & 15;
        const float* xp = x + (size_t)(row0 + r) * HD + l * 8;
        float4 v0 = ((const float4*)xp)[0];
        float4 v1 = ((const float4*)xp)[1];
        float f[8] = {v0.x, v0.y, v0.z, v0.w, v1.x, v1.y, v1.z, v1.w};
        *(uint4*)&abuf[r * AROW + l * 8] = pack8(f);
    }
    __syncthreads();

    U16 afr[4];
#pragma unroll
    for (int kc = 0; kc < 4; ++kc)
        afr[kc].u = *(const uint4*)&abuf[l16 * AROW + kc * 32 + quad * 8];

    const uint4* B4 = (const uint4*)wls;
    floatx4 zf = {0.f, 0.f, 0.f, 0.f};
    floatx4 acc[2] = {zf, zf};
#pragma unroll
    for (int kc = 0; kc < 4; ++kc)
#pragma unroll
        for (int c = 0; c < 2; ++c) {
            U16 bu; bu.u = B4[((2 * wave + c) * 4 + kc) * 64 + lane];
            acc[c] = __builtin_amdgcn_mfma_f32_16x16x32_bf16(afr[kc].h, bu.h, acc[c], 0, 0, 0);
        }

    const int lrow = quad * 4;
#pragma unroll
    for (int c = 0; c < 2; ++c) {
        int col = (2 * wave + c) * 16 + l16;
#pragma unroll
        for (int reg = 0; reg < 4; ++reg)
            cbuf[(lrow + reg) * HD + col] = f2bf(acc[c][reg]);
    }
    __syncthreads();
    {
        const uint4* c4 = (const uint4*)cbuf;
        uint4* o4 = (uint4*)y;
        int row = t >> 4, part = t & 15;
        o4[(size_t)(row0 + row) * 16 + part] = c4[t];
    }
}

// ---------------- scan: block scan + decoupled lookback, one dispatch ----------
// bflag[b] holds (inclusive block prefix + 1); 0 = not ready. 49 blocks, all
// co-resident (49 << 256 CUs), so the spin chain cannot deadlock.

__global__ __launch_bounds__(1024) void scan_kernel(
    const int* __restrict__ cnt, int* __restrict__ bflag,
    int* __restrict__ rowp, int n) {
    __shared__ int s[1024];
    __shared__ int sprefix;
    const int t = threadIdx.x;
    const int bid = blockIdx.x;
    int i = bid * 1024 + t;
    int v = (i < n) ? cnt[i] : 0;
    s[t] = v;
    __syncthreads();
    for (int off = 1; off < 1024; off <<= 1) {
        int add = (t >= off) ? s[t - off] : 0;
        __syncthreads();
        s[t] += add;
        __syncthreads();
    }
    if (t == 0) {
        int pre = 0;
        if (bid > 0) {
            int f;
            do { f = atomicAdd(&bflag[bid - 1], 0); } while (f == 0);
            pre = f - 1;
        }
        atomicExch(&bflag[bid], pre + s[1023] + 1);
        sprefix = pre;
    }
    __syncthreads();
    if (i < n) rowp[i + 1] = s[t] + sprefix;
    if (i == 0) rowp[0] = 0;
}

// build: pure scatter (rank precomputed in prep)
__global__ void build_kernel(const int* __restrict__ src, const int* __restrict__ dst,
                             const int* __restrict__ rowp, const int* __restrict__ rank,
                             int* __restrict__ colv, int n) {
    int i = blockIdx.x * 256 + threadIdx.x;
    if (i < n) colv[rowp[dst[i]] + rank[i]] = src[i];
}

// ---------------- agg: z = y + sum_nbr y + bias; stats of z --------------------
// 4-edge unroll: 4 independent row loads in flight per lane.

__global__ __launch_bounds__(256) void agg_kernel(
    const ushort* __restrict__ y, const int* __restrict__ rowp,
    const int* __restrict__ colv, const float* __restrict__ bias,
    ushort* __restrict__ z, float* __restrict__ ssum_p, float* __restrict__ ssq_p) {
    __shared__ float reds[4][HD];
    __shared__ float redq[4][HD];
    const int t = threadIdx.x;
    const int wave = t >> 6, lane = t & 63;
    const int node = blockIdx.x * 16 + (t >> 4);
    const int l = t & 15;
    const uint4* hp = (const uint4*)y;

    float a[8];
    unpack8(hp[(size_t)node * 16 + l], a);
    int beg = rowp[node], end = rowp[node + 1];
    int j = beg;
    for (; j + 3 < end; j += 4) {
        int c0 = colv[j], c1 = colv[j + 1], c2 = colv[j + 2], c3 = colv[j + 3];
        uint4 v0 = hp[(size_t)c0 * 16 + l];
        uint4 v1 = hp[(size_t)c1 * 16 + l];
        uint4 v2 = hp[(size_t)c2 * 16 + l];
        uint4 v3 = hp[(size_t)c3 * 16 + l];
        float b0[8], b1[8], b2[8], b3[8];
        unpack8(v0, b0); unpack8(v1, b1); unpack8(v2, b2); unpack8(v3, b3);
#pragma unroll
        for (int i = 0; i < 8; ++i) a[i] += (b0[i] + b1[i]) + (b2[i] + b3[i]);
    }
    for (; j < end; ++j) {
        float b[8];
        unpack8(hp[(size_t)colv[j] * 16 + l], b);
#pragma unroll
        for (int i = 0; i < 8; ++i) a[i] += b[i];
    }
    {
        float4 b0 = ((const float4*)(bias + l * 8))[0];
        float4 b1 = ((const float4*)(bias + l * 8))[1];
        a[0] += b0.x; a[1] += b0.y; a[2] += b0.z; a[3] += b0.w;
        a[4] += b1.x; a[5] += b1.y; a[6] += b1.z; a[7] += b1.w;
    }
    ((uint4*)z)[(size_t)node * 16 + l] = pack8(a);

    float s[8], q[8];
#pragma unroll
    for (int i = 0; i < 8; ++i) { s[i] = a[i]; q[i] = a[i] * a[i]; }
#pragma unroll
    for (int i = 0; i < 8; ++i) {
        s[i] += __shfl_xor(s[i], 16); s[i] += __shfl_xor(s[i], 32);
        q[i] += __shfl_xor(q[i], 16); q[i] += __shfl_xor(q[i], 32);
    }
    if (lane < 16) {
#pragma unroll
        for (int i = 0; i < 8; ++i) {
            reds[wave][lane * 8 + i] = s[i];
            redq[wave][lane * 8 + i] = q[i];
        }
    }
    __syncthreads();
    int slot = (blockIdx.x & (NSPLIT - 1)) * HD;
    if (t < HD) {
        atomicAdd(&ssum_p[slot + t], reds[0][t] + reds[1][t] + reds[2][t] + reds[3][t]);
    } else if (t < 2 * HD) {
        int c = t - HD;
        atomicAdd(&ssq_p[slot + c], redq[0][c] + redq[1][c] + redq[2][c] + redq[3][c]);
    }
}

// ---------------- gemmBA: BN+relu -> @Wb +bb relu -> @Wa' -> y' ----------------

__global__ __launch_bounds__(256, 3) void gemmBA_kernel(
    const ushort* __restrict__ z, const ushort* __restrict__ WfB,
    const ushort* __restrict__ WfA2, const float* __restrict__ biasB,
    ushort* __restrict__ yout,
    const float* __restrict__ gamma, const float* __restrict__ beta,
    const float* __restrict__ ssum_p, const float* __restrict__ ssq_p) {
    __shared__ ushort was[16384];     // 32 KB Wa' frags
    __shared__ ushort cbuf[16 * AROW];
    __shared__ float sca[HD];
    __shared__ float shf[HD];
    const int t = threadIdx.x;
    const int wave = t >> 6, lane = t & 63;
    const int quad = lane >> 4, l16 = lane & 15;
    const int row0 = blockIdx.x * 16;
    const int rowA = row0 + l16;

    {
        const uint4* g = (const uint4*)WfA2;
        uint4 v[8];
#pragma unroll
        for (int i = 0; i < 8; ++i) v[i] = g[i * 256 + t];
        uint4* s = (uint4*)was;
#pragma unroll
        for (int i = 0; i < 8; ++i) s[i * 256 + t] = v[i];
    }

    const uint4* Wf4 = (const uint4*)WfB;
    uint4 bfr[2][4];
#pragma unroll
    for (int c = 0; c < 2; ++c)
#pragma unroll
        for (int kc = 0; kc < 4; ++kc)
            bfr[c][kc] = Wf4[((2 * wave + c) * 4 + kc) * 64 + lane];

    U16 afr[4];
    {
        const ushort* ap = z + (size_t)rowA * HD + quad * 8;
#pragma unroll
        for (int kc = 0; kc < 4; ++kc)
            afr[kc].u = *(const uint4*)(ap + kc * 32);
    }

    if (t < HD) {
        float s = 0.f, q = 0.f;
#pragma unroll
        for (int i = 0; i < NSPLIT; ++i) { s += ssum_p[i * HD + t]; q += ssq_p[i * HD + t]; }
        float mean = s / (float)NNODES;
        float var = q / (float)NNODES - mean * mean;
        float rstd = rsqrtf(var + BN_EPS);
        float sc = gamma[t] * rstd;
        sca[t] = sc;
        shf[t] = beta[t] - mean * sc;
    }
    __syncthreads();

#pragma unroll
    for (int kc = 0; kc < 4; ++kc) {
        float f[8];
        unpack8(afr[kc].u, f);
        int kb = kc * 32 + quad * 8;
        float4 s0 = ((const float4*)(sca + kb))[0];
        float4 s1 = ((const float4*)(sca + kb))[1];
        float4 h0 = ((const float4*)(shf + kb))[0];
        float4 h1 = ((const float4*)(shf + kb))[1];
        f[0] = fmaxf(fmaf(f[0], s0.x, h0.x), 0.f);
        f[1] = fmaxf(fmaf(f[1], s0.y, h0.y), 0.f);
        f[2] = fmaxf(fmaf(f[2], s0.z, h0.z), 0.f);
        f[3] = fmaxf(fmaf(f[3], s0.w, h0.w), 0.f);
        f[4] = fmaxf(fmaf(f[4], s1.x, h1.x), 0.f);
        f[5] = fmaxf(fmaf(f[5], s1.y, h1.y), 0.f);
        f[6] = fmaxf(fmaf(f[6], s1.z, h1.z), 0.f);
        f[7] = fmaxf(fmaf(f[7], s1.w, h1.w), 0.f);
        afr[kc].u = pack8(f);
    }

    floatx4 zf = {0.f, 0.f, 0.f, 0.f};
    floatx4 acc[2] = {zf, zf};
#pragma unroll
    for (int kc = 0; kc < 4; ++kc)
#pragma unroll
        for (int c = 0; c < 2; ++c) {
            U16 bu; bu.u = bfr[c][kc];
            acc[c] = __builtin_amdgcn_mfma_f32_16x16x32_bf16(afr[kc].h, bu.h, acc[c], 0, 0, 0);
        }

    const int lrow = quad * 4;
#pragma unroll
    for (int c = 0; c < 2; ++c) {
        int col = (2 * wave + c) * 16 + l16;
        float b = biasB[col];
#pragma unroll
        for (int reg = 0; reg < 4; ++reg)
            cbuf[(lrow + reg) * AROW + col] = f2bf(fmaxf(acc[c][reg] + b, 0.f));
    }
    __syncthreads();

    U16 a2[4];
#pragma unroll
    for (int kc = 0; kc < 4; ++kc)
        a2[kc].u = *(const uint4*)&cbuf[l16 * AROW + kc * 32 + quad * 8];
    const uint4* W2 = (const uint4*)was;
    floatx4 acc2[2] = {zf, zf};
#pragma unroll
    for (int kc = 0; kc < 4; ++kc)
#pragma unroll
        for (int c = 0; c < 2; ++c) {
            U16 bu; bu.u = W2[((2 * wave + c) * 4 + kc) * 64 + lane];
            acc2[c] = __builtin_amdgcn_mfma_f32_16x16x32_bf16(a2[kc].h, bu.h, acc2[c], 0, 0, 0);
        }
    __syncthreads();

#pragma unroll
    for (int c = 0; c < 2; ++c) {
        int col = (2 * wave + c) * 16 + l16;
#pragma unroll
        for (int reg = 0; reg < 4; ++reg)
            cbuf[(lrow + reg) * AROW + col] = f2bf(acc2[c][reg]);
    }
    __syncthreads();
    {
        uint4* o4 = (uint4*)yout;
        int row = t >> 4, part = t & 15;
        o4[(size_t)(row0 + row) * 16 + part] = *(const uint4*)&cbuf[row * AROW + part * 8];
    }
}

// ---------------- gemmB2: BN+relu -> @Wb2 +bb2 relu -> segment readout ---------

__global__ __launch_bounds__(256, 4) void gemmB2_kernel(
    const ushort* __restrict__ z, const ushort* __restrict__ WfB,
    const float* __restrict__ biasB,
    const float* __restrict__ gamma, const float* __restrict__ beta,
    const float* __restrict__ ssum_p, const float* __restrict__ ssq_p,
    const int* __restrict__ gptr, float* __restrict__ gout) {
    __shared__ float sca[HD];
    __shared__ float shf[HD];
    const int t = threadIdx.x;
    const int wave = t >> 6, lane = t & 63;
    const int quad = lane >> 4, l16 = lane & 15;
    const int row0 = blockIdx.x * 16;
    const int rowA = row0 + l16;

    const uint4* Wf4 = (const uint4*)WfB;
    uint4 bfr[2][4];
#pragma unroll
    for (int c = 0; c < 2; ++c)
#pragma unroll
        for (int kc = 0; kc < 4; ++kc)
            bfr[c][kc] = Wf4[((2 * wave + c) * 4 + kc) * 64 + lane];

    U16 afr[4];
    {
        const ushort* ap = z + (size_t)rowA * HD + quad * 8;
#pragma unroll
        for (int kc = 0; kc < 4; ++kc)
            afr[kc].u = *(const uint4*)(ap + kc * 32);
    }

    if (t < HD) {
        float s = 0.f, q = 0.f;
#pragma unroll
        for (int i = 0; i < NSPLIT; ++i) { s += ssum_p[i * HD + t]; q += ssq_p[i * HD + t]; }
        float mean = s / (float)NNODES;
        float var = q / (float)NNODES - mean * mean;
        float rstd = rsqrtf(var + BN_EPS);
        float sc = gamma[t] * rstd;
        sca[t] = sc;
        shf[t] = beta[t] - mean * sc;
    }
    __syncthreads();

#pragma unroll
    for (int kc = 0; kc < 4; ++kc) {
        float f[8];
        unpack8(afr[kc].u, f);
        int kb = kc * 32 + quad * 8;
        float4 s0 = ((const float4*)(sca + kb))[0];
        float4 s1 = ((const float4*)(sca + kb))[1];
        float4 h0 = ((const float4*)(shf + kb))[0];
        float4 h1 = ((const float4*)(shf + kb))[1];
        f[0] = fmaxf(fmaf(f[0], s0.x, h0.x), 0.f);
        f[1] = fmaxf(fmaf(f[1], s0.y, h0.y), 0.f);
        f[2] = fmaxf(fmaf(f[2], s0.z, h0.z), 0.f);
        f[3] = fmaxf(fmaf(f[3], s0.w, h0.w), 0.f);
        f[4] = fmaxf(fmaf(f[4], s1.x, h1.x), 0.f);
        f[5] = fmaxf(fmaf(f[5], s1.y, h1.y), 0.f);
        f[6] = fmaxf(fmaf(f[6], s1.z, h1.z), 0.f);
        f[7] = fmaxf(fmaf(f[7], s1.w, h1.w), 0.f);
        afr[kc].u = pack8(f);
    }

    floatx4 zf = {0.f, 0.f, 0.f, 0.f};
    floatx4 acc[2] = {zf, zf};
#pragma unroll
    for (int kc = 0; kc < 4; ++kc)
#pragma unroll
        for (int c = 0; c < 2; ++c) {
            U16 bu; bu.u = bfr[c][kc];
            acc[c] = __builtin_amdgcn_mfma_f32_16x16x32_bf16(afr[kc].h, bu.h, acc[c], 0, 0, 0);
        }

    int r_base = row0 + quad * 4;
    int lo = 0, hi = NG - 1;
    while (lo < hi) {
        int mid = (lo + hi) >> 1;
        if (r_base >= gptr[mid + 1]) lo = mid + 1; else hi = mid;
    }
    int segr[4];
    int sg = lo;
#pragma unroll
    for (int reg = 0; reg < 4; ++reg) {
        while (r_base + reg >= gptr[sg + 1]) ++sg;
        segr[reg] = sg;
    }
#pragma unroll
    for (int c = 0; c < 2; ++c) {
        int col = (2 * wave + c) * 16 + l16;
        float b = biasB[col];
        float run = 0.f;
        int cur = segr[0];
#pragma unroll
        for (int reg = 0; reg < 4; ++reg) {
            if (segr[reg] != cur) {
                if (run != 0.f) atomicAdd(&gout[cur * HD + col], run);
                run = 0.f;
                cur = segr[reg];
            }
            run += fmaxf(acc[c][reg] + b, 0.f);
        }
        if (run != 0.f) atomicAdd(&gout[cur * HD + col], run);
    }
}

// ---------------- launch ----------------

extern "C" void kernel_launch(void* const* d_in, const int* in_sizes, int n_in,
                              void* d_out, int out_size, void* d_ws, size_t ws_size,
                              hipStream_t stream) {
    const float* x = (const float*)d_in[0];
    const int* esrc = (const int*)d_in[1];
    const int* edst = (const int*)d_in[2];
    const int* gptr = (const int*)d_in[3];
    const float* wA[3] = {(const float*)d_in[4], (const float*)d_in[10], (const float*)d_in[16]};
    const float* bA[3] = {(const float*)d_in[5], (const float*)d_in[11], (const float*)d_in[17]};
    const float* gm[3] = {(const float*)d_in[6], (const float*)d_in[12], (const float*)d_in[18]};
    const float* bt[3] = {(const float*)d_in[7], (const float*)d_in[13], (const float*)d_in[19]};
    const float* wB[3] = {(const float*)d_in[8], (const float*)d_in[14], (const float*)d_in[20]};
    const float* bB[3] = {(const float*)d_in[9], (const float*)d_in[15], (const float*)d_in[21]};

    char* w = (char*)d_ws;
    ushort* ybuf = (ushort*)w; w += (size_t)NNODES * HD * 2;  // 12.8 MB
    ushort* zbuf = (ushort*)w; w += (size_t)NNODES * HD * 2;  // 12.8 MB
    ushort* wf   = (ushort*)w; w += (size_t)6 * 16384 * 2;    // 192 KB
    int* colv  = (int*)w;   w += (size_t)NEDGES * 4;
    int* rank  = (int*)w;   w += (size_t)NEDGES * 4;
    int* rowp  = (int*)w;   w += ((size_t)(NNODES + 1) * 4 + 15) & ~(size_t)15;
    // ---- zero region ----
    char* zero_base = w;
    int* cnt   = (int*)w;   w += (size_t)NNODES * 4;
    int* bflag = (int*)w;   w += 64 * 4;
    float* ssum_p = (float*)w; w += 3 * NSPLIT * 128 * 4;
    float* ssq_p  = (float*)w; w += 3 * NSPLIT * 128 * 4;
    size_t zero_bytes = (size_t)(w - zero_base);

    hipMemsetAsync(zero_base, 0, zero_bytes, stream);
    hipMemsetAsync(d_out, 0, (size_t)NG * HD * 4, stream);

    WP6 wp;
    wp.w[0] = wA[0]; wp.w[1] = wB[0]; wp.w[2] = wA[1];
    wp.w[3] = wB[1]; wp.w[4] = wA[2]; wp.w[5] = wB[2];

    // prep: hist+rank (3125) + wfrag W1..5 (5) + gemm0A (3125)
    prep_kernel<<<6255, 256, 0, stream>>>(edst, cnt, rank, wp, wf, x, ybuf);
    scan_kernel<<<NSB, 1024, 0, stream>>>(cnt, bflag, rowp, NNODES);
    build_kernel<<<(NEDGES + 255) / 256, 256, 0, stream>>>(esrc, edst, rowp, rank, colv, NEDGES);

    for (int l = 0; l < 3; ++l) {
        agg_kernel<<<NTILE, 256, 0, stream>>>(
            ybuf, rowp, colv, bA[l], zbuf,
            ssum_p + l * NSPLIT * 128, ssq_p + l * NSPLIT * 128);
        if (l < 2) {
            gemmBA_kernel<<<NTILE, 256, 0, stream>>>(
                zbuf, wf + (size_t)(2 * l + 1) * 16384, wf + (size_t)(2 * l + 2) * 16384,
                bB[l], ybuf, gm[l], bt[l],
                ssum_p + l * NSPLIT * 128, ssq_p + l * NSPLIT * 128);
        } else {
            gemmB2_kernel<<<NTILE, 256, 0, stream>>>(
                zbuf, wf + (size_t)(2 * l + 1) * 16384, bB[l], gm[l], bt[l],
                ssum_p + l * NSPLIT * 128, ssq_p + l * NSPLIT * 128,
                gptr, (float*)d_out);
        }
    }
}

// Round 14
// 400.432 us; speedup vs baseline: 1.0381x; 1.0381x over previous
//
#include <hip/hip_runtime.h>

#define NNODES 50000
#define NEDGES 800000
#define HD 128
#define NG 512
#define BN_EPS 1e-5f
#define NTILE 3125           // 16-row tiles: 50000 = 3125 * 16 exactly
#define NSPLIT 8             // stats atomic split
#define NSB 49               // scan blocks
#define AROW 136             // padded LDS tile row in ushorts (272 B)

typedef short bf16x8 __attribute__((ext_vector_type(8)));
typedef float floatx4 __attribute__((ext_vector_type(4)));

union U16 { uint4 u; bf16x8 h; };

__device__ __forceinline__ ushort f2bf(float f) {
    unsigned u = __float_as_uint(f);
    return (ushort)((u + 0x7fffu + ((u >> 16) & 1u)) >> 16);
}
__device__ __forceinline__ void unpack8(const uint4& u, float* f) {
    const unsigned* w = (const unsigned*)&u;
#pragma unroll
    for (int i = 0; i < 4; ++i) {
        f[2 * i]     = __uint_as_float(w[i] << 16);
        f[2 * i + 1] = __uint_as_float(w[i] & 0xffff0000u);
    }
}
__device__ __forceinline__ uint4 pack8(const float* f) {
    uint4 o;
    unsigned* w = (unsigned*)&o;
#pragma unroll
    for (int i = 0; i < 4; ++i)
        w[i] = (unsigned)f2bf(f[2 * i]) | ((unsigned)f2bf(f[2 * i + 1]) << 16);
    return o;
}

// ---------------- prep: hist(+rank) + wfrag(5) + gemm0A, one dispatch -----------
// blocks [0,3125): histogram of edge dst, record per-edge rank
// blocks [3125,3130): pack W[1..5] into MFMA B-frag order (global)
// blocks [3130,6255): gemm0A — y0 = x @ Wa0; Wa0 staged fp32->bf16 frag order in
// LDS via flat-chunk scheme (one contiguous uint4 write per chunk: conflict-free)

struct WP6 { const float* w[6]; };

__global__ __launch_bounds__(256, 4) void prep_kernel(
    const int* __restrict__ edst, int* __restrict__ cnt, int* __restrict__ rank,
    WP6 p, ushort* __restrict__ wf,
    const float* __restrict__ x, ushort* __restrict__ y) {
    __shared__ ushort wls[16384];     // 32 KB Wa0 frags
    __shared__ ushort abuf[16 * AROW];// 4.25 KB x tile, reused as C tile
    const int b = blockIdx.x, t = threadIdx.x;

    if (b < 3125) {
        int i = b * 256 + t;
        rank[i] = atomicAdd(&cnt[edst[i]], 1);
        return;
    }
    if (b < 3130) {
        int m = b - 3125 + 1;          // matrices 1..5
        const float* W = p.w[m];
        ushort* o = wf + (size_t)m * 16384;
        for (int i = t; i < 16384; i += 256) {
            int j = i & 7, lane = (i >> 3) & 63, kc = (i >> 9) & 3, ct = i >> 11;
            int k = kc * 32 + (lane >> 4) * 8 + j;
            int n = ct * 16 + (lane & 15);
            o[i] = f2bf(W[k * HD + n]);
        }
        return;
    }

    // ---- gemm0A ----
    const int row0 = (b - 3130) * 16;
    const int wave = t >> 6, lane = t & 63;
    const int quad = lane >> 4, l16 = lane & 15;

    // stage Wa0 into LDS frag order, conflict-free (uint4 per flat chunk)
    {
        const float* W = p.w[0];
        uint4* s4 = (uint4*)wls;
#pragma unroll
        for (int i = 0; i < 8; ++i) {
            int f = i * 256 + t;          // chunk index 0..2047
            int ln = f & 63;
            int kcct = f >> 6;            // ct*4 + kc
            int kc = kcct & 3, ct = kcct >> 2;
            int kbase = kc * 32 + (ln >> 4) * 8;
            int n = ct * 16 + (ln & 15);
            float fv[8];
#pragma unroll
            for (int j = 0; j < 8; ++j)
                fv[j] = W[(size_t)(kbase + j) * HD + n];
            s4[f] = pack8(fv);
        }
    }

    // x tile: thread t -> row t>>4, floats (t&15)*8 .. +8
    {
        int r = t >> 4, l = t & 15;
        const float* xp = x + (size_t)(row0 + r) * HD + l * 8;
        float4 v0 = ((const float4*)xp)[0];
        float4 v1 = ((const float4*)xp)[1];
        float f[8] = {v0.x, v0.y, v0.z, v0.w, v1.x, v1.y, v1.z, v1.w};
        *(uint4*)&abuf[r * AROW + l * 8] = pack8(f);
    }
    __syncthreads();

    U16 afr[4];
#pragma unroll
    for (int kc = 0; kc < 4; ++kc)
        afr[kc].u = *(const uint4*)&abuf[l16 * AROW + kc * 32 + quad * 8];

    const uint4* B4 = (const uint4*)wls;
    floatx4 zf = {0.f, 0.f, 0.f, 0.f};
    floatx4 acc[2] = {zf, zf};
#pragma unroll
    for (int kc = 0; kc < 4; ++kc)
#pragma unroll
        for (int c = 0; c < 2; ++c) {
            U16 bu; bu.u = B4[((2 * wave + c) * 4 + kc) * 64 + lane];
            acc[c] = __builtin_amdgcn_mfma_f32_16x16x32_bf16(afr[kc].h, bu.h, acc[c], 0, 0, 0);
        }
    __syncthreads();  // all waves done reading abuf; reuse it as C tile

    const int lrow = quad * 4;
#pragma unroll
    for (int c = 0; c < 2; ++c) {
        int col = (2 * wave + c) * 16 + l16;
#pragma unroll
        for (int reg = 0; reg < 4; ++reg)
            abuf[(lrow + reg) * AROW + col] = f2bf(acc[c][reg]);
    }
    __syncthreads();
    {
        uint4* o4 = (uint4*)y;
        int row = t >> 4, part = t & 15;
        o4[(size_t)(row0 + row) * 16 + part] = *(const uint4*)&abuf[row * AROW + part * 8];
    }
}

// ---------------- scan: block scan + decoupled lookback, one dispatch ----------

__global__ __launch_bounds__(1024) void scan_kernel(
    const int* __restrict__ cnt, int* __restrict__ bflag,
    int* __restrict__ rowp, int n) {
    __shared__ int s[1024];
    __shared__ int sprefix;
    const int t = threadIdx.x;
    const int bid = blockIdx.x;
    int i = bid * 1024 + t;
    int v = (i < n) ? cnt[i] : 0;
    s[t] = v;
    __syncthreads();
    for (int off = 1; off < 1024; off <<= 1) {
        int add = (t >= off) ? s[t - off] : 0;
        __syncthreads();
        s[t] += add;
        __syncthreads();
    }
    if (t == 0) {
        int pre = 0;
        if (bid > 0) {
            int f;
            do { f = atomicAdd(&bflag[bid - 1], 0); } while (f == 0);
            pre = f - 1;
        }
        atomicExch(&bflag[bid], pre + s[1023] + 1);
        sprefix = pre;
    }
    __syncthreads();
    if (i < n) rowp[i + 1] = s[t] + sprefix;
    if (i == 0) rowp[0] = 0;
}

// build: pure scatter (rank precomputed in prep)
__global__ void build_kernel(const int* __restrict__ src, const int* __restrict__ dst,
                             const int* __restrict__ rowp, const int* __restrict__ rank,
                             int* __restrict__ colv, int n) {
    int i = blockIdx.x * 256 + threadIdx.x;
    if (i < n) colv[rowp[dst[i]] + rank[i]] = src[i];
}

// ---------------- agg: z = y + sum_nbr y + bias; stats of z --------------------

__global__ __launch_bounds__(256) void agg_kernel(
    const ushort* __restrict__ y, const int* __restrict__ rowp,
    const int* __restrict__ colv, const float* __restrict__ bias,
    ushort* __restrict__ z, float* __restrict__ ssum_p, float* __restrict__ ssq_p) {
    __shared__ float reds[4][HD];
    __shared__ float redq[4][HD];
    const int t = threadIdx.x;
    const int wave = t >> 6, lane = t & 63;
    const int node = blockIdx.x * 16 + (t >> 4);
    const int l = t & 15;
    const uint4* hp = (const uint4*)y;

    float a[8];
    unpack8(hp[(size_t)node * 16 + l], a);
    int beg = rowp[node], end = rowp[node + 1];
    int j = beg;
    for (; j + 3 < end; j += 4) {
        int c0 = colv[j], c1 = colv[j + 1], c2 = colv[j + 2], c3 = colv[j + 3];
        uint4 v0 = hp[(size_t)c0 * 16 + l];
        uint4 v1 = hp[(size_t)c1 * 16 + l];
        uint4 v2 = hp[(size_t)c2 * 16 + l];
        uint4 v3 = hp[(size_t)c3 * 16 + l];
        float b0[8], b1[8], b2[8], b3[8];
        unpack8(v0, b0); unpack8(v1, b1); unpack8(v2, b2); unpack8(v3, b3);
#pragma unroll
        for (int i = 0; i < 8; ++i) a[i] += (b0[i] + b1[i]) + (b2[i] + b3[i]);
    }
    for (; j < end; ++j) {
        float b[8];
        unpack8(hp[(size_t)colv[j] * 16 + l], b);
#pragma unroll
        for (int i = 0; i < 8; ++i) a[i] += b[i];
    }
    {
        float4 b0 = ((const float4*)(bias + l * 8))[0];
        float4 b1 = ((const float4*)(bias + l * 8))[1];
        a[0] += b0.x; a[1] += b0.y; a[2] += b0.z; a[3] += b0.w;
        a[4] += b1.x; a[5] += b1.y; a[6] += b1.z; a[7] += b1.w;
    }
    ((uint4*)z)[(size_t)node * 16 + l] = pack8(a);

    float s[8], q[8];
#pragma unroll
    for (int i = 0; i < 8; ++i) { s[i] = a[i]; q[i] = a[i] * a[i]; }
#pragma unroll
    for (int i = 0; i < 8; ++i) {
        s[i] += __shfl_xor(s[i], 16); s[i] += __shfl_xor(s[i], 32);
        q[i] += __shfl_xor(q[i], 16); q[i] += __shfl_xor(q[i], 32);
    }
    if (lane < 16) {
#pragma unroll
        for (int i = 0; i < 8; ++i) {
            reds[wave][lane * 8 + i] = s[i];
            redq[wave][lane * 8 + i] = q[i];
        }
    }
    __syncthreads();
    int slot = (blockIdx.x & (NSPLIT - 1)) * HD;
    if (t < HD) {
        atomicAdd(&ssum_p[slot + t], reds[0][t] + reds[1][t] + reds[2][t] + reds[3][t]);
    } else if (t < 2 * HD) {
        int c = t - HD;
        atomicAdd(&ssq_p[slot + c], redq[0][c] + redq[1][c] + redq[2][c] + redq[3][c]);
    }
}

// ---------------- gemmBA: BN+relu -> @Wb +bb relu -> @Wa' -> y' ----------------

__global__ __launch_bounds__(256, 3) void gemmBA_kernel(
    const ushort* __restrict__ z, const ushort* __restrict__ WfB,
    const ushort* __restrict__ WfA2, const float* __restrict__ biasB,
    ushort* __restrict__ yout,
    const float* __restrict__ gamma, const float* __restrict__ beta,
    const float* __restrict__ ssum_p, const float* __restrict__ ssq_p) {
    __shared__ ushort was[16384];     // 32 KB Wa' frags
    __shared__ ushort cbuf[16 * AROW];
    __shared__ float sca[HD];
    __shared__ float shf[HD];
    const int t = threadIdx.x;
    const int wave = t >> 6, lane = t & 63;
    const int quad = lane >> 4, l16 = lane & 15;
    const int row0 = blockIdx.x * 16;
    const int rowA = row0 + l16;

    {
        const uint4* g = (const uint4*)WfA2;
        uint4 v[8];
#pragma unroll
        for (int i = 0; i < 8; ++i) v[i] = g[i * 256 + t];
        uint4* s = (uint4*)was;
#pragma unroll
        for (int i = 0; i < 8; ++i) s[i * 256 + t] = v[i];
    }

    const uint4* Wf4 = (const uint4*)WfB;
    uint4 bfr[2][4];
#pragma unroll
    for (int c = 0; c < 2; ++c)
#pragma unroll
        for (int kc = 0; kc < 4; ++kc)
            bfr[c][kc] = Wf4[((2 * wave + c) * 4 + kc) * 64 + lane];

    U16 afr[4];
    {
        const ushort* ap = z + (size_t)rowA * HD + quad * 8;
#pragma unroll
        for (int kc = 0; kc < 4; ++kc)
            afr[kc].u = *(const uint4*)(ap + kc * 32);
    }

    if (t < HD) {
        float s = 0.f, q = 0.f;
#pragma unroll
        for (int i = 0; i < NSPLIT; ++i) { s += ssum_p[i * HD + t]; q += ssq_p[i * HD + t]; }
        float mean = s / (float)NNODES;
        float var = q / (float)NNODES - mean * mean;
        float rstd = rsqrtf(var + BN_EPS);
        float sc = gamma[t] * rstd;
        sca[t] = sc;
        shf[t] = beta[t] - mean * sc;
    }
    __syncthreads();

#pragma unroll
    for (int kc = 0; kc < 4; ++kc) {
        float f[8];
        unpack8(afr[kc].u, f);
        int kb = kc * 32 + quad * 8;
        float4 s0 = ((const float4*)(sca + kb))[0];
        float4 s1 = ((const float4*)(sca + kb))[1];
        float4 h0 = ((const float4*)(shf + kb))[0];
        float4 h1 = ((const float4*)(shf + kb))[1];
        f[0] = fmaxf(fmaf(f[0], s0.x, h0.x), 0.f);
        f[1] = fmaxf(fmaf(f[1], s0.y, h0.y), 0.f);
        f[2] = fmaxf(fmaf(f[2], s0.z, h0.z), 0.f);
        f[3] = fmaxf(fmaf(f[3], s0.w, h0.w), 0.f);
        f[4] = fmaxf(fmaf(f[4], s1.x, h1.x), 0.f);
        f[5] = fmaxf(fmaf(f[5], s1.y, h1.y), 0.f);
        f[6] = fmaxf(fmaf(f[6], s1.z, h1.z), 0.f);
        f[7] = fmaxf(fmaf(f[7], s1.w, h1.w), 0.f);
        afr[kc].u = pack8(f);
    }

    floatx4 zf = {0.f, 0.f, 0.f, 0.f};
    floatx4 acc[2] = {zf, zf};
#pragma unroll
    for (int kc = 0; kc < 4; ++kc)
#pragma unroll
        for (int c = 0; c < 2; ++c) {
            U16 bu; bu.u = bfr[c][kc];
            acc[c] = __builtin_amdgcn_mfma_f32_16x16x32_bf16(afr[kc].h, bu.h, acc[c], 0, 0, 0);
        }

    const int lrow = quad * 4;
#pragma unroll
    for (int c = 0; c < 2; ++c) {
        int col = (2 * wave + c) * 16 + l16;
        float b = biasB[col];
#pragma unroll
        for (int reg = 0; reg < 4; ++reg)
            cbuf[(lrow + reg) * AROW + col] = f2bf(fmaxf(acc[c][reg] + b, 0.f));
    }
    __syncthreads();

    U16 a2[4];
#pragma unroll
    for (int kc = 0; kc < 4; ++kc)
        a2[kc].u = *(const uint4*)&cbuf[l16 * AROW + kc * 32 + quad * 8];
    const uint4* W2 = (const uint4*)was;
    floatx4 acc2[2] = {zf, zf};
#pragma unroll
    for (int kc = 0; kc < 4; ++kc)
#pragma unroll
        for (int c = 0; c < 2; ++c) {
            U16 bu; bu.u = W2[((2 * wave + c) * 4 + kc) * 64 + lane];
            acc2[c] = __builtin_amdgcn_mfma_f32_16x16x32_bf16(a2[kc].h, bu.h, acc2[c], 0, 0, 0);
        }
    __syncthreads();

#pragma unroll
    for (int c = 0; c < 2; ++c) {
        int col = (2 * wave + c) * 16 + l16;
#pragma unroll
        for (int reg = 0; reg < 4; ++reg)
            cbuf[(lrow + reg) * AROW + col] = f2bf(acc2[c][reg]);
    }
    __syncthreads();
    {
        uint4* o4 = (uint4*)yout;
        int row = t >> 4, part = t & 15;
        o4[(size_t)(row0 + row) * 16 + part] = *(const uint4*)&cbuf[row * AROW + part * 8];
    }
}

// ---------------- gemmB2: BN+relu -> @Wb2 +bb2 relu -> segment readout ---------

__global__ __launch_bounds__(256, 4) void gemmB2_kernel(
    const ushort* __restrict__ z, const ushort* __restrict__ WfB,
    const float* __restrict__ biasB,
    const float* __restrict__ gamma, const float* __restrict__ beta,
    const float* __restrict__ ssum_p, const float* __restrict__ ssq_p,
    const int* __restrict__ gptr, float* __restrict__ gout) {
    __shared__ float sca[HD];
    __shared__ float shf[HD];
    const int t = threadIdx.x;
    const int wave = t >> 6, lane = t & 63;
    const int quad = lane >> 4, l16 = lane & 15;
    const int row0 = blockIdx.x * 16;
    const int rowA = row0 + l16;

    const uint4* Wf4 = (const uint4*)WfB;
    uint4 bfr[2][4];
#pragma unroll
    for (int c = 0; c < 2; ++c)
#pragma unroll
        for (int kc = 0; kc < 4; ++kc)
            bfr[c][kc] = Wf4[((2 * wave + c) * 4 + kc) * 64 + lane];

    U16 afr[4];
    {
        const ushort* ap = z + (size_t)rowA * HD + quad * 8;
#pragma unroll
        for (int kc = 0; kc < 4; ++kc)
            afr[kc].u = *(const uint4*)(ap + kc * 32);
    }

    if (t < HD) {
        float s = 0.f, q = 0.f;
#pragma unroll
        for (int i = 0; i < NSPLIT; ++i) { s += ssum_p[i * HD + t]; q += ssq_p[i * HD + t]; }
        float mean = s / (float)NNODES;
        float var = q / (float)NNODES - mean * mean;
        float rstd = rsqrtf(var + BN_EPS);
        float sc = gamma[t] * rstd;
        sca[t] = sc;
        shf[t] = beta[t] - mean * sc;
    }
    __syncthreads();

#pragma unroll
    for (int kc = 0; kc < 4; ++kc) {
        float f[8];
        unpack8(afr[kc].u, f);
        int kb = kc * 32 + quad * 8;
        float4 s0 = ((const float4*)(sca + kb))[0];
        float4 s1 = ((const float4*)(sca + kb))[1];
        float4 h0 = ((const float4*)(shf + kb))[0];
        float4 h1 = ((const float4*)(shf + kb))[1];
        f[0] = fmaxf(fmaf(f[0], s0.x, h0.x), 0.f);
        f[1] = fmaxf(fmaf(f[1], s0.y, h0.y), 0.f);
        f[2] = fmaxf(fmaf(f[2], s0.z, h0.z), 0.f);
        f[3] = fmaxf(fmaf(f[3], s0.w, h0.w), 0.f);
        f[4] = fmaxf(fmaf(f[4], s1.x, h1.x), 0.f);
        f[5] = fmaxf(fmaf(f[5], s1.y, h1.y), 0.f);
        f[6] = fmaxf(fmaf(f[6], s1.z, h1.z), 0.f);
        f[7] = fmaxf(fmaf(f[7], s1.w, h1.w), 0.f);
        afr[kc].u = pack8(f);
    }

    floatx4 zf = {0.f, 0.f, 0.f, 0.f};
    floatx4 acc[2] = {zf, zf};
#pragma unroll
    for (int kc = 0; kc < 4; ++kc)
#pragma unroll
        for (int c = 0; c < 2; ++c) {
            U16 bu; bu.u = bfr[c][kc];
            acc[c] = __builtin_amdgcn_mfma_f32_16x16x32_bf16(afr[kc].h, bu.h, acc[c], 0, 0, 0);
        }

    int r_base = row0 + quad * 4;
    int lo = 0, hi = NG - 1;
    while (lo < hi) {
        int mid = (lo + hi) >> 1;
        if (r_base >= gptr[mid + 1]) lo = mid + 1; else hi = mid;
    }
    int segr[4];
    int sg = lo;
#pragma unroll
    for (int reg = 0; reg < 4; ++reg) {
        while (r_base + reg >= gptr[sg + 1]) ++sg;
        segr[reg] = sg;
    }
#pragma unroll
    for (int c = 0; c < 2; ++c) {
        int col = (2 * wave + c) * 16 + l16;
        float b = biasB[col];
        float run = 0.f;
        int cur = segr[0];
#pragma unroll
        for (int reg = 0; reg < 4; ++reg) {
            if (segr[reg] != cur) {
                if (run != 0.f) atomicAdd(&gout[cur * HD + col], run);
                run = 0.f;
                cur = segr[reg];
            }
            run += fmaxf(acc[c][reg] + b, 0.f);
        }
        if (run != 0.f) atomicAdd(&gout[cur * HD + col], run);
    }
}

// ---------------- launch ----------------

extern "C" void kernel_launch(void* const* d_in, const int* in_sizes, int n_in,
                              void* d_out, int out_size, void* d_ws, size_t ws_size,
                              hipStream_t stream) {
    const float* x = (const float*)d_in[0];
    const int* esrc = (const int*)d_in[1];
    const int* edst = (const int*)d_in[2];
    const int* gptr = (const int*)d_in[3];
    const float* wA[3] = {(const float*)d_in[4], (const float*)d_in[10], (const float*)d_in[16]};
    const float* bA[3] = {(const float*)d_in[5], (const float*)d_in[11], (const float*)d_in[17]};
    const float* gm[3] = {(const float*)d_in[6], (const float*)d_in[12], (const float*)d_in[18]};
    const float* bt[3] = {(const float*)d_in[7], (const float*)d_in[13], (const float*)d_in[19]};
    const float* wB[3] = {(const float*)d_in[8], (const float*)d_in[14], (const float*)d_in[20]};
    const float* bB[3] = {(const float*)d_in[9], (const float*)d_in[15], (const float*)d_in[21]};

    char* w = (char*)d_ws;
    ushort* ybuf = (ushort*)w; w += (size_t)NNODES * HD * 2;  // 12.8 MB
    ushort* zbuf = (ushort*)w; w += (size_t)NNODES * HD * 2;  // 12.8 MB
    ushort* wf   = (ushort*)w; w += (size_t)6 * 16384 * 2;    // 192 KB
    int* colv  = (int*)w;   w += (size_t)NEDGES * 4;
    int* rank  = (int*)w;   w += (size_t)NEDGES * 4;
    int* rowp  = (int*)w;   w += ((size_t)(NNODES + 1) * 4 + 15) & ~(size_t)15;
    // ---- zero region ----
    char* zero_base = w;
    int* cnt   = (int*)w;   w += (size_t)NNODES * 4;
    int* bflag = (int*)w;   w += 64 * 4;
    float* ssum_p = (float*)w; w += 3 * NSPLIT * 128 * 4;
    float* ssq_p  = (float*)w; w += 3 * NSPLIT * 128 * 4;
    size_t zero_bytes = (size_t)(w - zero_base);

    hipMemsetAsync(zero_base, 0, zero_bytes, stream);
    hipMemsetAsync(d_out, 0, (size_t)NG * HD * 4, stream);

    WP6 wp;
    wp.w[0] = wA[0]; wp.w[1] = wB[0]; wp.w[2] = wA[1];
    wp.w[3] = wB[1]; wp.w[4] = wA[2]; wp.w[5] = wB[2];

    prep_kernel<<<6255, 256, 0, stream>>>(edst, cnt, rank, wp, wf, x, ybuf);
    scan_kernel<<<NSB, 1024, 0, stream>>>(cnt, bflag, rowp, NNODES);
    build_kernel<<<(NEDGES + 255) / 256, 256, 0, stream>>>(esrc, edst, rowp, rank, colv, NEDGES);

    for (int l = 0; l < 3; ++l) {
        agg_kernel<<<NTILE, 256, 0, stream>>>(
            ybuf, rowp, colv, bA[l], zbuf,
            ssum_p + l * NSPLIT * 128, ssq_p + l * NSPLIT * 128);
        if (l < 2) {
            gemmBA_kernel<<<NTILE, 256, 0, stream>>>(
                zbuf, wf + (size_t)(2 * l + 1) * 16384, wf + (size_t)(2 * l + 2) * 16384,
                bB[l], ybuf, gm[l], bt[l],
                ssum_p + l * NSPLIT * 128, ssq_p + l * NSPLIT * 128);
        } else {
            gemmB2_kernel<<<NTILE, 256, 0, stream>>>(
                zbuf, wf + (size_t)(2 * l + 1) * 16384, bB[l], gm[l], bt[l],
                ssum_p + l * NSPLIT * 128, ssq_p + l * NSPLIT * 128,
                gptr, (float*)d_out);
        }
    }
}